// Round 25
// baseline (110.079 us; speedup 1.0000x reference)
//
#include <hip/hip_runtime.h>
#include <math.h>

#define B_ 2
#define S_ 2048
#define DM 1024
#define NH 16
#define HD 64

typedef unsigned short u16;
typedef unsigned int u32;
typedef __attribute__((ext_vector_type(8))) short bf16x8;
typedef __attribute__((ext_vector_type(4))) float f32x4;

// (1/sqrt(model_dim)) * log2(e): folded into Q at GEMM0 epilogue
#define C2SCALE 0.0450842200277800f

__device__ __forceinline__ u16 f2bf(float x) {
  unsigned u = __float_as_uint(x);
  u = (u + 0x7FFFu + ((u >> 16) & 1u)) >> 16;
  return (u16)u;
}

__device__ __forceinline__ u32 cvtpk(float lo, float hi) {
  u32 r;
  asm("v_cvt_pk_bf16_f32 %0, %1, %2" : "=v"(r) : "v"(lo), "v"(hi));
  return r;
}

__device__ __forceinline__ float exp2a(float x) {
  float r;
  asm("v_exp_f32 %0, %1" : "=v"(r) : "v"(x));
  return r;
}

__device__ __forceinline__ void gload_lds16(const u16* g, u16* l) {
  __builtin_amdgcn_global_load_lds((const __attribute__((address_space(1))) void*)g,
                                   (__attribute__((address_space(3))) void*)l, 16, 0, 0);
}

// sigma position within a 64-chunk (same permutation as the V^T producer)
__device__ __forceinline__ int sigpos(int w6) {
  return ((w6 >> 5) << 5) | (((w6 >> 2) & 3) << 3) | (((w6 >> 4) & 1) << 2) | (w6 & 3);
}

// per-batch exclusive prefix scan of kv_mask -> compacted positions posb,
// totals nvb, and sigma-ordered COMPACTED mask words (0xFFFF below total).
__global__ void mask_scan(const int* __restrict__ kvm, int* __restrict__ posb,
                          int* __restrict__ nvb, u16* __restrict__ mwg) {
  const int b = blockIdx.x;
  const int tid = threadIdx.x;  // 256
  const int lane = tid & 63, wv = tid >> 6;
  __shared__ int wsum[4];
  int v[8], s = 0;
  const int base = b * S_ + tid * 8;
#pragma unroll
  for (int j = 0; j < 8; j++) { v[j] = kvm[base + j] ? 1 : 0; s += v[j]; }
  int sc = s;
#pragma unroll
  for (int off = 1; off < 64; off <<= 1) {
    int t = __shfl_up(sc, off, 64);
    if (lane >= off) sc += t;
  }
  if (lane == 63) wsum[wv] = sc;
  __syncthreads();
  int woff = 0;
#pragma unroll
  for (int w = 0; w < 4; w++) woff += (w < wv) ? wsum[w] : 0;
  int run = woff + sc - s;  // exclusive prefix for this thread's chunk
#pragma unroll
  for (int j = 0; j < 8; j++) { posb[base + j] = run; run += v[j]; }
  const int total = wsum[0] + wsum[1] + wsum[2] + wsum[3];
  if (tid == 0) nvb[b] = total;
  for (int i = tid; i < S_; i += 256)
    mwg[b * S_ + (i & ~63) + sigpos(i & 63)] = (i < total) ? 0xFFFFu : 0u;
}

// fused f32->bf16 converts + compacted-X gather + V^T pad-column zeroing.
__global__ void cvt_all(const float* __restrict__ q, const float* __restrict__ Wq,
                        const float* __restrict__ Wk, const float* __restrict__ Wv,
                        const float* __restrict__ Wo, const int* __restrict__ kvm,
                        const int* __restrict__ posb, const int* __restrict__ nvb,
                        u16* __restrict__ Xbf, u16* __restrict__ Wcat,
                        u16* __restrict__ Wobf, u16* __restrict__ vtbuf,
                        u16* __restrict__ Xc) {
  const int NQ4 = (B_ * S_ * DM) / 4;
  const int NW4 = (DM * DM) / 4;
  const int total = NQ4 + 4 * NW4;
  int i = blockIdx.x * blockDim.x + threadIdx.x;
  int stride = gridDim.x * blockDim.x;
  // zero V^T pad columns [nv, ceil64(nv)) for every (bh, d) (PV NaN safety)
  for (int idx = i; idx < B_ * NH * HD * 64; idx += stride) {
    int col = idx & 63;
    int dd = (idx >> 6) & 63;
    int bh = idx >> 12;
    int nv = nvb[bh >> 4];
    int padw = ((nv + 63) & ~63) - nv;
    if (col < padw)
      vtbuf[((size_t)bh * HD + dd) * S_ + nv + col] = 0;
  }
  for (; i < total; i += stride) {
    if (i < NQ4) {
      float4 v = ((const float4*)q)[i];
      ushort4 o;
      o.x = f2bf(v.x); o.y = f2bf(v.y); o.z = f2bf(v.z); o.w = f2bf(v.w);
      ((ushort4*)Xbf)[i] = o;
      int row = i >> 8, chunk = i & 255;
      int b = row >> 11, s = row & 2047;
      if (kvm[b * S_ + s]) {
        int p = posb[b * S_ + s];
        *(ushort4*)(Xc + ((size_t)(b * S_ + p)) * DM + chunk * 4) = o;
      }
    } else {
      int t = i - NQ4;
      const float* src;
      u16* dst;
      if (t < NW4)            { src = Wq + (size_t)t * 4; dst = Wcat + (size_t)t * 4; }
      else if (t < 2 * NW4)   { src = Wk + (size_t)(t - NW4) * 4;     dst = Wcat + DM * DM + (size_t)(t - NW4) * 4; }
      else if (t < 3 * NW4)   { src = Wv + (size_t)(t - 2 * NW4) * 4; dst = Wcat + 2 * DM * DM + (size_t)(t - 2 * NW4) * 4; }
      else                    { src = Wo + (size_t)(t - 3 * NW4) * 4; dst = Wobf + (size_t)(t - 3 * NW4) * 4; }
      float4 v = *(const float4*)src;
      ushort4 o;
      o.x = f2bf(v.x); o.y = f2bf(v.y); o.z = f2bf(v.z); o.w = f2bf(v.w);
      *(ushort4*)dst = o;
    }
  }
}

// Unified projection GEMM, 256x128 tile, BK=64, 8 waves x 64x64 sub-tiles
// (4M x 2N). Max fragment reuse: per wave-iter 16 b128 reads + 6 writes for
// 32 MFMAs; 2x work per barrier vs 128x128. LDS 96 KB dbuf -> 1 block/CU;
// active blocks = 128 Q + ~128 compacted-KV = ~256 = 1/CU.
// Decode: Ls<128 -> Q (16 Mt x 8 Nt); else KV (2 batches x 8 Mt x 16 Nt),
// blocks with Mb >= nv early-exit. XOR-swizzled slots, lgkm-only barrier.
__global__ __launch_bounds__(512, 2) void gemm_qkv(
    const u16* __restrict__ Xbf, const u16* __restrict__ Xc,
    const u16* __restrict__ Wcat, u16* __restrict__ qo, u16* __restrict__ ko,
    u16* __restrict__ vo, const int* __restrict__ nvb) {
  const int K = DM;
  const int Lraw = blockIdx.x;
  const int Ls = (Lraw & 7) * 48 + (Lraw >> 3);   // bijective (384 % 8 == 0)

  int Mb, nglob, bkv = 0, nv = 1 << 30;
  const u16* Ap;
  if (Ls < 128) {
    Mb = (Ls & 15) << 8;               // 16 M-tiles of 256 over 4096 rows
    nglob = (Ls >> 4) << 7;            // 8 N-tiles of 128 over Wq
    Ap = Xbf;
  } else {
    int L2 = Ls - 128;                 // 0..255
    bkv = L2 >> 7;
    int L3 = L2 & 127;
    Mb = (L3 & 7) << 8;                // 8 M-tiles of 256 over compacted rows
    nglob = 1024 + ((L3 >> 3) << 7);   // 16 N-tiles of 128 over [Wk|Wv]
    nv = nvb[bkv];
    if (Mb >= nv) return;
    Ap = Xc + (size_t)bkv * S_ * DM;
  }

  __shared__ __align__(16) u16 As[2][256 * 64];
  __shared__ __align__(16) u16 Bs[2][128 * 64];
  const int tid = threadIdx.x;
  const int wv = tid >> 6, lane = tid & 63;
  const int g = lane >> 4, c = lane & 15;
  const int wr = wv >> 1, wc = wv & 1;   // wr 0..3 (64-row band), wc 0..1 (64-col)

  f32x4 acc[4][4];
#pragma unroll
  for (int i = 0; i < 4; i++)
#pragma unroll
    for (int j = 0; j < 4; j++) acc[i][j] = f32x4{0.f, 0.f, 0.f, 0.f};

  // staging: A 2048 chunks (4/thread: rows r,+64,+128,+192), B 1024 (2/thread)
  const int r0 = tid >> 3;            // 0..63
  const int col8 = tid & 7;
  const int slot = col8 ^ (r0 & 7);   // +64k rows preserve r&7
  const u16* ag[4];
  u16* al[4];
#pragma unroll
  for (int i = 0; i < 4; i++) {
    ag[i] = Ap + (size_t)(Mb + r0 + 64 * i) * K + col8 * 8;        // +t*64
    al[i] = &As[0][(r0 + 64 * i) * 64 + slot * 8];
  }
  const u16* bg[2];
  u16* bl[2];
#pragma unroll
  for (int i = 0; i < 2; i++) {
    bg[i] = Wcat + (size_t)(nglob + r0 + 64 * i) * K + col8 * 8;
    bl[i] = &Bs[0][(r0 + 64 * i) * 64 + slot * 8];
  }

  // prologue: tile0 -> regs -> buf0; tile1 -> regs
  bf16x8 ar[4], br[2];
#pragma unroll
  for (int i = 0; i < 4; i++) ar[i] = *(const bf16x8*)ag[i];
#pragma unroll
  for (int i = 0; i < 2; i++) br[i] = *(const bf16x8*)bg[i];
#pragma unroll
  for (int i = 0; i < 4; i++) *(bf16x8*)al[i] = ar[i];
#pragma unroll
  for (int i = 0; i < 2; i++) *(bf16x8*)bl[i] = br[i];
#pragma unroll
  for (int i = 0; i < 4; i++) ar[i] = *(const bf16x8*)(ag[i] + 64);
#pragma unroll
  for (int i = 0; i < 2; i++) br[i] = *(const bf16x8*)(bg[i] + 64);
  __syncthreads();

  const int swz = c & 7;
  const int NTI = 16;

  for (int t = 0; t < NTI; ++t) {
    const int cur = t & 1;
    if (t + 1 < NTI) {
      const int nbA = (cur ^ 1) * 16384;
      const int nbB = (cur ^ 1) * 8192;
#pragma unroll
      for (int i = 0; i < 4; i++) *(bf16x8*)(al[i] + nbA) = ar[i];
#pragma unroll
      for (int i = 0; i < 2; i++) *(bf16x8*)(bl[i] + nbB) = br[i];
      if (t + 2 < NTI) {
        const int go = (t + 2) * 64;
#pragma unroll
        for (int i = 0; i < 4; i++) ar[i] = *(const bf16x8*)(ag[i] + go);
#pragma unroll
        for (int i = 0; i < 2; i++) br[i] = *(const bf16x8*)(bg[i] + go);
      }
    }
    const u16* AB = &As[cur][0];
    const u16* BB = &Bs[cur][0];
#pragma unroll
    for (int ks = 0; ks < 2; ks++) {
      const int koff = ((4 * ks + g) ^ swz) * 8;
      bf16x8 af[4], bfr[4];
#pragma unroll
      for (int mi = 0; mi < 4; mi++)
        af[mi] = *(const bf16x8*)&AB[(wr * 64 + mi * 16 + c) * 64 + koff];
#pragma unroll
      for (int ni = 0; ni < 4; ni++)
        bfr[ni] = *(const bf16x8*)&BB[(wc * 64 + ni * 16 + c) * 64 + koff];
#pragma unroll
      for (int mi = 0; mi < 4; mi++)
#pragma unroll
        for (int ni = 0; ni < 4; ni++)
          acc[mi][ni] = __builtin_amdgcn_mfma_f32_16x16x32_bf16(af[mi], bfr[ni], acc[mi][ni], 0, 0, 0);
    }
    asm volatile("s_waitcnt lgkmcnt(0)\n\ts_barrier" ::: "memory");
  }

  const int nbase = nglob + wc * 64 + c;
  const int which = nbase >> 10;  // block-uniform (128-col tiles never cross 1024)
  if (which == 0) {
#pragma unroll
    for (int mi = 0; mi < 4; mi++) {
#pragma unroll
      for (int ni = 0; ni < 4; ni++) {
        int nn = nbase + ni * 16;
        int h = nn >> 6, d = nn & 63;
#pragma unroll
        for (int r = 0; r < 4; r++) {
          int row = Mb + wr * 64 + mi * 16 + g * 4 + r;
          int b0 = row >> 11, s0 = row & 2047;
          qo[(((size_t)(b0 * NH + h)) * S_ + s0) * HD + d] =
              f2bf(acc[mi][ni][r] * C2SCALE);
        }
      }
    }
  } else if (which == 1) {
#pragma unroll
    for (int mi = 0; mi < 4; mi++) {
#pragma unroll
      for (int r = 0; r < 4; r++) {
        int p = Mb + wr * 64 + mi * 16 + g * 4 + r;
        if (p < nv) {
#pragma unroll
          for (int ni = 0; ni < 4; ni++) {
            int nn = (nbase + ni * 16) & 1023;
            ko[((size_t)(bkv * NH + (nn >> 6)) * S_ + p) * HD + (nn & 63)] =
                f2bf(acc[mi][ni][r]);
          }
        }
      }
    }
  } else {
#pragma unroll
    for (int mi = 0; mi < 4; mi++) {
#pragma unroll
      for (int r = 0; r < 4; r++) {
        int p = Mb + wr * 64 + mi * 16 + g * 4 + r;
        if (p < nv) {
          int dst = (p & ~63) + sigpos(p & 63);
#pragma unroll
          for (int ni = 0; ni < 4; ni++) {
            int nn = (nbase + ni * 16) & 1023;
            vo[((size_t)((bkv * NH + (nn >> 6)) * HD + (nn & 63))) * S_ + dst] =
                f2bf(acc[mi][ni][r]);
          }
        }
      }
    }
  }
}

// GEMM1: out[4096,1024] = A @ Wo^T + bo. 128x64 tile, 512 blocks, BK=64
// (16 k-iters), reg-staged dbuf XOR-swizzled LDS, lgkm-only barrier. (r21)
__global__ __launch_bounds__(256, 3) void gemm_n64(
    const u16* __restrict__ A, const u16* __restrict__ Bw,
    const float* __restrict__ bias, float* __restrict__ fo) {
  __shared__ __align__(16) u16 As[2][128 * 64];
  __shared__ __align__(16) u16 Bs[2][64 * 64];
  const int K = DM, N = DM;
  const int tid = threadIdx.x;
  const int wv = tid >> 6, lane = tid & 63;
  const int g = lane >> 4, c = lane & 15;
  const int wr = wv >> 1, wc = wv & 1;
  const int L = blockIdx.x;
  const int Ls = (L & 7) * 64 + (L >> 3);
  const int Mb = (Ls & 31) << 7, Nb = (Ls >> 5) << 6;

  f32x4 acc[4][2];
#pragma unroll
  for (int i = 0; i < 4; i++)
#pragma unroll
    for (int j = 0; j < 2; j++) acc[i][j] = f32x4{0.f, 0.f, 0.f, 0.f};

  const int r0 = tid >> 3;
  const int col8 = tid & 7;
  const int slot = col8 ^ (r0 & 7);
  const u16* ag0 = A + (size_t)(Mb + r0) * K + col8 * 8;
  const u16* ag1 = ag0 + (size_t)32 * K;
  const u16* ag2 = ag0 + (size_t)64 * K;
  const u16* ag3 = ag0 + (size_t)96 * K;
  const u16* bg0 = Bw + (size_t)(Nb + r0) * K + col8 * 8;
  const u16* bg1 = bg0 + (size_t)32 * K;
  u16* al0 = &As[0][r0 * 64 + slot * 8];
  u16* al1 = al0 + 32 * 64;
  u16* al2 = al0 + 64 * 64;
  u16* al3 = al0 + 96 * 64;
  u16* bl0 = &Bs[0][r0 * 64 + slot * 8];
  u16* bl1 = bl0 + 32 * 64;

  bf16x8 arA = *(const bf16x8*)ag0, arB = *(const bf16x8*)ag1;
  bf16x8 arC = *(const bf16x8*)ag2, arD = *(const bf16x8*)ag3;
  bf16x8 brA = *(const bf16x8*)bg0, brB = *(const bf16x8*)bg1;
  *(bf16x8*)al0 = arA; *(bf16x8*)al1 = arB;
  *(bf16x8*)al2 = arC; *(bf16x8*)al3 = arD;
  *(bf16x8*)bl0 = brA; *(bf16x8*)bl1 = brB;
  arA = *(const bf16x8*)(ag0 + 64); arB = *(const bf16x8*)(ag1 + 64);
  arC = *(const bf16x8*)(ag2 + 64); arD = *(const bf16x8*)(ag3 + 64);
  brA = *(const bf16x8*)(bg0 + 64); brB = *(const bf16x8*)(bg1 + 64);
  __syncthreads();

  const int swz = c & 7;
  const int NTI = 16;

  for (int t = 0; t < NTI; ++t) {
    const int cur = t & 1;
    if (t + 1 < NTI) {
      const int nbA = (cur ^ 1) * 8192;
      const int nbB = (cur ^ 1) * 4096;
      *(bf16x8*)(al0 + nbA) = arA; *(bf16x8*)(al1 + nbA) = arB;
      *(bf16x8*)(al2 + nbA) = arC; *(bf16x8*)(al3 + nbA) = arD;
      *(bf16x8*)(bl0 + nbB) = brA; *(bf16x8*)(bl1 + nbB) = brB;
      if (t + 2 < NTI) {
        arA = *(const bf16x8*)(ag0 + (t + 2) * 64);
        arB = *(const bf16x8*)(ag1 + (t + 2) * 64);
        arC = *(const bf16x8*)(ag2 + (t + 2) * 64);
        arD = *(const bf16x8*)(ag3 + (t + 2) * 64);
        brA = *(const bf16x8*)(bg0 + (t + 2) * 64);
        brB = *(const bf16x8*)(bg1 + (t + 2) * 64);
      }
    }
    const u16* AB = &As[cur][0];
    const u16* BB = &Bs[cur][0];
#pragma unroll
    for (int ks = 0; ks < 2; ks++) {
      const int koff = ((4 * ks + g) ^ swz) * 8;
      bf16x8 af[4], bfr[2];
#pragma unroll
      for (int mi = 0; mi < 4; mi++)
        af[mi] = *(const bf16x8*)&AB[(wr * 64 + mi * 16 + c) * 64 + koff];
#pragma unroll
      for (int ni = 0; ni < 2; ni++)
        bfr[ni] = *(const bf16x8*)&BB[(wc * 32 + ni * 16 + c) * 64 + koff];
#pragma unroll
      for (int mi = 0; mi < 4; mi++)
#pragma unroll
        for (int ni = 0; ni < 2; ni++)
          acc[mi][ni] = __builtin_amdgcn_mfma_f32_16x16x32_bf16(af[mi], bfr[ni], acc[mi][ni], 0, 0, 0);
    }
    asm volatile("s_waitcnt lgkmcnt(0)\n\ts_barrier" ::: "memory");
  }

#pragma unroll
  for (int mi = 0; mi < 4; mi++) {
#pragma unroll
    for (int ni = 0; ni < 2; ni++) {
      int n = Nb + wc * 32 + ni * 16 + c;
      float bv = bias[n];
#pragma unroll
      for (int r = 0; r < 4; r++) {
        int row = Mb + wr * 64 + mi * 16 + g * 4 + r;
        fo[(size_t)row * N + n] = acc[mi][ni][r] + bv;
      }
    }
  }
}

// Flash attention over COMPACTED kv, 4 waves x 32 q-rows (r19 structure).
__global__ __launch_bounds__(256, 3) void attn_kernel(
    const u16* __restrict__ qb, const u16* __restrict__ kb,
    const u16* __restrict__ vtb, const u16* __restrict__ mwg,
    const int* __restrict__ nvb, u16* __restrict__ ob) {
  __shared__ __align__(16) u16 Kl[2][64 * 64];
  __shared__ __align__(16) u16 Vl[2][64 * 64];
  __shared__ __align__(16) u16 MW[S_];

  const int tid = threadIdx.x;
  const int wv = tid >> 6, lane = tid & 63;
  const int g = lane >> 4, c = lane & 15;

  const int L = blockIdx.x;
  const int j = L >> 3;
  const int bh = ((L & 7) << 2) | (j >> 4);
  const int qi = j & 15;
  const int b = bh >> 4, h = bh & 15;
  const int q0 = qi * 128;
  const size_t bhbase = (size_t)bh * (S_ * HD);
  const int NT = (nvb[b] + 63) >> 6;

  ((uint4*)MW)[tid] = ((const uint4*)(mwg + b * S_))[tid];

  bf16x8 qf[2][2];
#pragma unroll
  for (int mi = 0; mi < 2; mi++)
#pragma unroll
    for (int ks = 0; ks < 2; ks++)
      qf[mi][ks] = *(const bf16x8*)(qb + bhbase +
                   (size_t)(q0 + wv * 32 + mi * 16 + c) * HD + ks * 32 + g * 8);

  f32x4 Oa[4][2];
#pragma unroll
  for (int di = 0; di < 4; di++)
#pragma unroll
    for (int mi = 0; mi < 2; mi++) Oa[di][mi] = f32x4{0.f, 0.f, 0.f, 0.f};
  f32x4 lacc[2];
  lacc[0] = f32x4{0.f, 0.f, 0.f, 0.f};
  lacc[1] = f32x4{0.f, 0.f, 0.f, 0.f};

  union { u32 u[4]; bf16x8 v; } ones;
#pragma unroll
  for (int w = 0; w < 4; w++) ones.u[w] = 0x3F803F80u;

  const int srow = tid >> 3;
  const int scol8 = tid & 7;
  const u16* kg1 = kb + bhbase + (size_t)srow * HD + scol8 * 8;
  const u16* kg2 = kg1 + (size_t)32 * HD;
  const u16* vg1 = vtb + bhbase + (size_t)srow * S_ + scol8 * 8;
  const u16* vg2 = vg1 + (size_t)32 * S_;
  const int wslot = scol8 ^ (srow & 7);
  u16* kld1 = &Kl[0][srow * 64 + wslot * 8];
  u16* kld2 = kld1 + 32 * 64;
  u16* vld1 = &Vl[0][srow * 64 + wslot * 8];
  u16* vld2 = vld1 + 32 * 64;

  bf16x8 krg[2], vrg[2];
  krg[0] = *(const bf16x8*)kg1;  krg[1] = *(const bf16x8*)kg2;
  vrg[0] = *(const bf16x8*)vg1;  vrg[1] = *(const bf16x8*)vg2;
  *(bf16x8*)kld1 = krg[0];  *(bf16x8*)kld2 = krg[1];
  *(bf16x8*)vld1 = vrg[0];  *(bf16x8*)vld2 = vrg[1];
  krg[0] = *(const bf16x8*)(kg1 + 4096);  krg[1] = *(const bf16x8*)(kg2 + 4096);
  vrg[0] = *(const bf16x8*)(vg1 + 64);    vrg[1] = *(const bf16x8*)(vg2 + 64);
  __syncthreads();

  const int swz = c & 7;

  for (int t = 0; t < NT; ++t) {
    const int cur = t & 1;
    if (t + 1 < NT) {
      const int nb = (cur ^ 1) * 4096;
      *(bf16x8*)(kld1 + nb) = krg[0];  *(bf16x8*)(kld2 + nb) = krg[1];
      *(bf16x8*)(vld1 + nb) = vrg[0];  *(bf16x8*)(vld2 + nb) = vrg[1];
      if (t + 2 < NT) {
        krg[0] = *(const bf16x8*)(kg1 + (t + 2) * 4096);
        krg[1] = *(const bf16x8*)(kg2 + (t + 2) * 4096);
        vrg[0] = *(const bf16x8*)(vg1 + (t + 2) * 64);
        vrg[1] = *(const bf16x8*)(vg2 + (t + 2) * 64);
      }
    }
    const u16* KB = &Kl[cur][0];
    const u16* VB = &Vl[cur][0];

    f32x4 Sa[4][2];
#pragma unroll
    for (int ni = 0; ni < 4; ni++)
#pragma unroll
      for (int mi = 0; mi < 2; mi++) Sa[ni][mi] = f32x4{0.f, 0.f, 0.f, 0.f};
    __builtin_amdgcn_s_setprio(1);
#pragma unroll
    for (int ks = 0; ks < 2; ks++) {
      bf16x8 kf[4];
#pragma unroll
      for (int ni = 0; ni < 4; ni++)
        kf[ni] = *(const bf16x8*)&KB[(ni * 16 + c) * 64 + (((4 * ks + g) ^ swz) * 8)];
#pragma unroll
      for (int ni = 0; ni < 4; ni++)
#pragma unroll
        for (int mi = 0; mi < 2; mi++)
          Sa[ni][mi] = __builtin_amdgcn_mfma_f32_16x16x32_bf16(kf[ni], qf[mi][ks], Sa[ni][mi], 0, 0, 0);
    }
    __builtin_amdgcn_s_setprio(0);

    bf16x8 Pa[2][2];
#pragma unroll
    for (int ks = 0; ks < 2; ks++) {
      uint4 mw = *(const uint4*)&MW[t * 64 + ks * 32 + g * 8];
#pragma unroll
      for (int mi = 0; mi < 2; mi++) {
        union { u32 u[4]; bf16x8 v; } pw;
        pw.u[0] = cvtpk(exp2a(Sa[2 * ks][mi][0]), exp2a(Sa[2 * ks][mi][1])) & mw.x;
        pw.u[1] = cvtpk(exp2a(Sa[2 * ks][mi][2]), exp2a(Sa[2 * ks][mi][3])) & mw.y;
        pw.u[2] = cvtpk(exp2a(Sa[2 * ks + 1][mi][0]), exp2a(Sa[2 * ks + 1][mi][1])) & mw.z;
        pw.u[3] = cvtpk(exp2a(Sa[2 * ks + 1][mi][2]), exp2a(Sa[2 * ks + 1][mi][3])) & mw.w;
        Pa[mi][ks] = pw.v;
      }
    }

    __builtin_amdgcn_s_setprio(1);
#pragma unroll
    for (int mi = 0; mi < 2; mi++) {
      lacc[mi] = __builtin_amdgcn_mfma_f32_16x16x32_bf16(ones.v, Pa[mi][0], lacc[mi], 0, 0, 0);
      lacc[mi] = __builtin_amdgcn_mfma_f32_16x16x32_bf16(ones.v, Pa[mi][1], lacc[mi], 0, 0, 0);
    }
#pragma unroll
    for (int ks = 0; ks < 2; ks++) {
      bf16x8 vf[4];
#pragma unroll
      for (int di = 0; di < 4; di++)
        vf[di] = *(const bf16x8*)&VB[(di * 16 + c) * 64 + (((4 * ks + g) ^ swz) * 8)];
#pragma unroll
      for (int di = 0; di < 4; di++)
#pragma unroll
        for (int mi = 0; mi < 2; mi++)
          Oa[di][mi] = __builtin_amdgcn_mfma_f32_16x16x32_bf16(vf[di], Pa[mi][ks], Oa[di][mi], 0, 0, 0);
    }
    __builtin_amdgcn_s_setprio(0);

    asm volatile("s_waitcnt lgkmcnt(0)\n\ts_barrier" ::: "memory");
  }

#pragma unroll
  for (int mi = 0; mi < 2; mi++) {
    float inv = 1.f / lacc[mi][0];
    int q = q0 + wv * 32 + mi * 16 + c;
    size_t base = ((size_t)(b * S_ + q)) * DM + (size_t)h * HD;
#pragma unroll
    for (int di = 0; di < 4; di++) {
      uint2 o;
      o.x = cvtpk(Oa[di][mi][0] * inv, Oa[di][mi][1] * inv);
      o.y = cvtpk(Oa[di][mi][2] * inv, Oa[di][mi][3] * inv);
      *(uint2*)(ob + base + di * 16 + g * 4) = o;
    }
  }
}

extern "C" void kernel_launch(void* const* d_in, const int* in_sizes, int n_in,
                              void* d_out, int out_size, void* d_ws, size_t ws_size,
                              hipStream_t stream) {
  const float* q  = (const float*)d_in[0];
  const int* kvm  = (const int*)d_in[1];
  const float* Wq = (const float*)d_in[2];
  const float* Wk = (const float*)d_in[3];
  const float* Wv = (const float*)d_in[4];
  const float* Wo = (const float*)d_in[5];
  const float* bo = (const float*)d_in[6];
  float* out = (float*)d_out;
  char* ws = (char*)d_ws;

  u16* Xbf   = (u16*)(ws);                       // 8 MB; reused as obuf post-gemm
  u16* Wcat  = (u16*)(ws + (8u << 20));          // 6 MB (Wq|Wk|Wv)
  u16* Wobf  = (u16*)(ws + (14u << 20));         // 2 MB
  u16* qbuf  = (u16*)(ws + (16u << 20));         // 8 MB (B,H,S,64), pre-scaled
  u16* kbuf  = (u16*)(ws + (24u << 20));         // 8 MB compacted
  u16* vtbuf = (u16*)(ws + (32u << 20));         // 8 MB (B,H,64,S) sigma, compacted
  u16* mwg   = (u16*)(ws + (40u << 20));         // 8 KB compacted mask words
  int* posb  = (int*)(ws + (41u << 20));         // 16 KB prefix positions
  int* nvb   = (int*)(ws + (42u << 20));         // 8 B totals
  u16* Xc    = (u16*)d_out;                      // 8 MB compacted X (d_out scratch)
  u16* obuf  = Xbf;

  mask_scan<<<B_, 256, 0, stream>>>(kvm, posb, nvb, mwg);
  cvt_all<<<2048, 256, 0, stream>>>(q, Wq, Wk, Wv, Wo, kvm, posb, nvb,
                                    Xbf, Wcat, Wobf, vtbuf, Xc);
  gemm_qkv<<<384, 512, 0, stream>>>(Xbf, Xc, Wcat, qbuf, kbuf, vtbuf, nvb);
  attn_kernel<<<512, 256, 0, stream>>>(qbuf, kbuf, vtbuf, mwg, nvb, obuf);
  gemm_n64<<<512, 256, 0, stream>>>(obuf, Wobf, bo, out);
}

// Round 26
// 97.578 us; speedup vs baseline: 1.1281x; 1.1281x over previous
//
#include <hip/hip_runtime.h>
#include <math.h>

#define B_ 2
#define S_ 2048
#define DM 1024
#define NH 16
#define HD 64

typedef unsigned short u16;
typedef unsigned int u32;
typedef __attribute__((ext_vector_type(8))) short bf16x8;
typedef __attribute__((ext_vector_type(4))) float f32x4;

// (1/sqrt(model_dim)) * log2(e): folded into Q at GEMM0 epilogue
#define C2SCALE 0.0450842200277800f

__device__ __forceinline__ u16 f2bf(float x) {
  unsigned u = __float_as_uint(x);
  u = (u + 0x7FFFu + ((u >> 16) & 1u)) >> 16;
  return (u16)u;
}

__device__ __forceinline__ u32 cvtpk(float lo, float hi) {
  u32 r;
  asm("v_cvt_pk_bf16_f32 %0, %1, %2" : "=v"(r) : "v"(lo), "v"(hi));
  return r;
}

__device__ __forceinline__ float exp2a(float x) {
  float r;
  asm("v_exp_f32 %0, %1" : "=v"(r) : "v"(x));
  return r;
}

// sigma position within a 64-chunk (same permutation as the V^T producer)
__device__ __forceinline__ int sigpos(int w6) {
  return ((w6 >> 5) << 5) | (((w6 >> 2) & 3) << 3) | (((w6 >> 4) & 1) << 2) | (w6 & 3);
}

// per-batch exclusive prefix scan of kv_mask -> compacted positions posb,
// totals nvb, and sigma-ordered COMPACTED mask words (0xFFFF below total).
__global__ void mask_scan(const int* __restrict__ kvm, int* __restrict__ posb,
                          int* __restrict__ nvb, u16* __restrict__ mwg) {
  const int b = blockIdx.x;
  const int tid = threadIdx.x;  // 256
  const int lane = tid & 63, wv = tid >> 6;
  __shared__ int wsum[4];
  int v[8], s = 0;
  const int base = b * S_ + tid * 8;
#pragma unroll
  for (int j = 0; j < 8; j++) { v[j] = kvm[base + j] ? 1 : 0; s += v[j]; }
  int sc = s;
#pragma unroll
  for (int off = 1; off < 64; off <<= 1) {
    int t = __shfl_up(sc, off, 64);
    if (lane >= off) sc += t;
  }
  if (lane == 63) wsum[wv] = sc;
  __syncthreads();
  int woff = 0;
#pragma unroll
  for (int w = 0; w < 4; w++) woff += (w < wv) ? wsum[w] : 0;
  int run = woff + sc - s;  // exclusive prefix for this thread's chunk
#pragma unroll
  for (int j = 0; j < 8; j++) { posb[base + j] = run; run += v[j]; }
  const int total = wsum[0] + wsum[1] + wsum[2] + wsum[3];
  if (tid == 0) nvb[b] = total;
  for (int i = tid; i < S_; i += 256)
    mwg[b * S_ + (i & ~63) + sigpos(i & 63)] = (i < total) ? 0xFFFFu : 0u;
}

// fused f32->bf16 converts + compacted-X gather + V^T pad-column zeroing.
__global__ void cvt_all(const float* __restrict__ q, const float* __restrict__ Wq,
                        const float* __restrict__ Wk, const float* __restrict__ Wv,
                        const float* __restrict__ Wo, const int* __restrict__ kvm,
                        const int* __restrict__ posb, const int* __restrict__ nvb,
                        u16* __restrict__ Xbf, u16* __restrict__ Wcat,
                        u16* __restrict__ Wobf, u16* __restrict__ vtbuf,
                        u16* __restrict__ Xc) {
  const int NQ4 = (B_ * S_ * DM) / 4;
  const int NW4 = (DM * DM) / 4;
  const int total = NQ4 + 4 * NW4;
  int i = blockIdx.x * blockDim.x + threadIdx.x;
  int stride = gridDim.x * blockDim.x;
  // zero V^T pad columns [nv, ceil64(nv)) for every (bh, d) (PV NaN safety)
  for (int idx = i; idx < B_ * NH * HD * 64; idx += stride) {
    int col = idx & 63;
    int dd = (idx >> 6) & 63;
    int bh = idx >> 12;
    int nv = nvb[bh >> 4];
    int padw = ((nv + 63) & ~63) - nv;
    if (col < padw)
      vtbuf[((size_t)bh * HD + dd) * S_ + nv + col] = 0;
  }
  for (; i < total; i += stride) {
    if (i < NQ4) {
      float4 v = ((const float4*)q)[i];
      ushort4 o;
      o.x = f2bf(v.x); o.y = f2bf(v.y); o.z = f2bf(v.z); o.w = f2bf(v.w);
      ((ushort4*)Xbf)[i] = o;
      int row = i >> 8, chunk = i & 255;
      int b = row >> 11, s = row & 2047;
      if (kvm[b * S_ + s]) {
        int p = posb[b * S_ + s];
        *(ushort4*)(Xc + ((size_t)(b * S_ + p)) * DM + chunk * 4) = o;
      }
    } else {
      int t = i - NQ4;
      const float* src;
      u16* dst;
      if (t < NW4)            { src = Wq + (size_t)t * 4; dst = Wcat + (size_t)t * 4; }
      else if (t < 2 * NW4)   { src = Wk + (size_t)(t - NW4) * 4;     dst = Wcat + DM * DM + (size_t)(t - NW4) * 4; }
      else if (t < 3 * NW4)   { src = Wv + (size_t)(t - 2 * NW4) * 4; dst = Wcat + 2 * DM * DM + (size_t)(t - 2 * NW4) * 4; }
      else                    { src = Wo + (size_t)(t - 3 * NW4) * 4; dst = Wobf + (size_t)(t - 3 * NW4) * 4; }
      float4 v = *(const float4*)src;
      ushort4 o;
      o.x = f2bf(v.x); o.y = f2bf(v.y); o.z = f2bf(v.z); o.w = f2bf(v.w);
      *(ushort4*)dst = o;
    }
  }
}

// Unified projection GEMM, BK=64, 8 waves (4M x 2N), 128x128 tile, reg-staged
// double-buffered XOR-swizzled LDS (64 KB), lgkm-only barrier. (champion)
__global__ __launch_bounds__(512, 4) void gemm_qkv(
    const u16* __restrict__ Xbf, const u16* __restrict__ Xc,
    const u16* __restrict__ Wcat, u16* __restrict__ qo, u16* __restrict__ ko,
    u16* __restrict__ vo, const int* __restrict__ nvb) {
  const int K = DM;
  const int Lraw = blockIdx.x;
  const int Ls = (Lraw & 7) * 96 + (Lraw >> 3);

  int Mb, nglob, bkv = 0, nv = 1 << 30;
  const u16* Ap;
  if (Ls < 256) {
    Mb = (Ls & 31) << 7;
    nglob = (Ls >> 5) << 7;
    Ap = Xbf;
  } else {
    int L2 = Ls - 256;
    bkv = L2 >> 8;
    int L3 = L2 & 255;
    Mb = (L3 & 15) << 7;
    nglob = 1024 + ((L3 >> 4) << 7);
    nv = nvb[bkv];
    if (Mb >= nv) return;
    Ap = Xc + (size_t)bkv * S_ * DM;
  }

  __shared__ __align__(16) u16 As[2][128 * 64];
  __shared__ __align__(16) u16 Bs[2][128 * 64];
  const int tid = threadIdx.x;
  const int wv = tid >> 6, lane = tid & 63;
  const int g = lane >> 4, c = lane & 15;
  const int wr = wv >> 1, wc = wv & 1;

  f32x4 acc[2][4];
#pragma unroll
  for (int i = 0; i < 2; i++)
#pragma unroll
    for (int j = 0; j < 4; j++) acc[i][j] = f32x4{0.f, 0.f, 0.f, 0.f};

  const int r1 = tid >> 3;
  const int col8 = tid & 7;
  const u16* ag1 = Ap + (size_t)(Mb + r1) * K + col8 * 8;
  const u16* ag2 = ag1 + (size_t)64 * K;
  const u16* bg1 = Wcat + (size_t)(nglob + r1) * K + col8 * 8;
  const u16* bg2 = bg1 + (size_t)64 * K;
  const int slot = col8 ^ (r1 & 7);
  u16* al1 = &As[0][r1 * 64 + slot * 8];
  u16* al2 = al1 + 64 * 64;
  u16* bl1 = &Bs[0][r1 * 64 + slot * 8];
  u16* bl2 = bl1 + 64 * 64;

  bf16x8 ar0 = *(const bf16x8*)ag1, ar1 = *(const bf16x8*)ag2;
  bf16x8 br0 = *(const bf16x8*)bg1, br1 = *(const bf16x8*)bg2;
  *(bf16x8*)al1 = ar0; *(bf16x8*)al2 = ar1;
  *(bf16x8*)bl1 = br0; *(bf16x8*)bl2 = br1;
  ar0 = *(const bf16x8*)(ag1 + 64); ar1 = *(const bf16x8*)(ag2 + 64);
  br0 = *(const bf16x8*)(bg1 + 64); br1 = *(const bf16x8*)(bg2 + 64);
  __syncthreads();

  const int swz = c & 7;
  const int NTI = 16;

  for (int t = 0; t < NTI; ++t) {
    const int cur = t & 1;
    if (t + 1 < NTI) {
      const int nb = (cur ^ 1) * 8192;
      *(bf16x8*)(al1 + nb) = ar0; *(bf16x8*)(al2 + nb) = ar1;
      *(bf16x8*)(bl1 + nb) = br0; *(bf16x8*)(bl2 + nb) = br1;
      if (t + 2 < NTI) {
        ar0 = *(const bf16x8*)(ag1 + (t + 2) * 64);
        ar1 = *(const bf16x8*)(ag2 + (t + 2) * 64);
        br0 = *(const bf16x8*)(bg1 + (t + 2) * 64);
        br1 = *(const bf16x8*)(bg2 + (t + 2) * 64);
      }
    }
    const u16* AB = &As[cur][0];
    const u16* BB = &Bs[cur][0];
#pragma unroll
    for (int ks = 0; ks < 2; ks++) {
      const int koff = ((4 * ks + g) ^ swz) * 8;
      bf16x8 af[2], bfr[4];
#pragma unroll
      for (int mi = 0; mi < 2; mi++)
        af[mi] = *(const bf16x8*)&AB[(wr * 32 + mi * 16 + c) * 64 + koff];
#pragma unroll
      for (int ni = 0; ni < 4; ni++)
        bfr[ni] = *(const bf16x8*)&BB[(wc * 64 + ni * 16 + c) * 64 + koff];
#pragma unroll
      for (int mi = 0; mi < 2; mi++)
#pragma unroll
        for (int ni = 0; ni < 4; ni++)
          acc[mi][ni] = __builtin_amdgcn_mfma_f32_16x16x32_bf16(af[mi], bfr[ni], acc[mi][ni], 0, 0, 0);
    }
    asm volatile("s_waitcnt lgkmcnt(0)\n\ts_barrier" ::: "memory");
  }

  const int nbase = nglob + wc * 64 + c;
  const int which = nbase >> 10;
  if (which == 0) {
#pragma unroll
    for (int mi = 0; mi < 2; mi++) {
#pragma unroll
      for (int ni = 0; ni < 4; ni++) {
        int nn = nbase + ni * 16;
        int h = nn >> 6, d = nn & 63;
#pragma unroll
        for (int r = 0; r < 4; r++) {
          int row = Mb + wr * 32 + mi * 16 + g * 4 + r;
          int b0 = row >> 11, s0 = row & 2047;
          qo[(((size_t)(b0 * NH + h)) * S_ + s0) * HD + d] =
              f2bf(acc[mi][ni][r] * C2SCALE);
        }
      }
    }
  } else if (which == 1) {
#pragma unroll
    for (int mi = 0; mi < 2; mi++) {
#pragma unroll
      for (int r = 0; r < 4; r++) {
        int p = Mb + wr * 32 + mi * 16 + g * 4 + r;
        if (p < nv) {
#pragma unroll
          for (int ni = 0; ni < 4; ni++) {
            int nn = (nbase + ni * 16) & 1023;
            ko[((size_t)(bkv * NH + (nn >> 6)) * S_ + p) * HD + (nn & 63)] =
                f2bf(acc[mi][ni][r]);
          }
        }
      }
    }
  } else {
#pragma unroll
    for (int mi = 0; mi < 2; mi++) {
#pragma unroll
      for (int r = 0; r < 4; r++) {
        int p = Mb + wr * 32 + mi * 16 + g * 4 + r;
        if (p < nv) {
          int dst = (p & ~63) + sigpos(p & 63);
#pragma unroll
          for (int ni = 0; ni < 4; ni++) {
            int nn = (nbase + ni * 16) & 1023;
            vo[((size_t)((bkv * NH + (nn >> 6)) * HD + (nn & 63))) * S_ + dst] =
                f2bf(acc[mi][ni][r]);
          }
        }
      }
    }
  }
}

// GEMM1: out[4096,1024] = A @ Wo^T + bo. 128x64 tile, 512 blocks, BK=64
// (16 k-iters), reg-staged dbuf XOR-swizzled LDS, lgkm-only barrier. (r21)
__global__ __launch_bounds__(256, 3) void gemm_n64(
    const u16* __restrict__ A, const u16* __restrict__ Bw,
    const float* __restrict__ bias, float* __restrict__ fo) {
  __shared__ __align__(16) u16 As[2][128 * 64];
  __shared__ __align__(16) u16 Bs[2][64 * 64];
  const int K = DM, N = DM;
  const int tid = threadIdx.x;
  const int wv = tid >> 6, lane = tid & 63;
  const int g = lane >> 4, c = lane & 15;
  const int wr = wv >> 1, wc = wv & 1;
  const int L = blockIdx.x;
  const int Ls = (L & 7) * 64 + (L >> 3);
  const int Mb = (Ls & 31) << 7, Nb = (Ls >> 5) << 6;

  f32x4 acc[4][2];
#pragma unroll
  for (int i = 0; i < 4; i++)
#pragma unroll
    for (int j = 0; j < 2; j++) acc[i][j] = f32x4{0.f, 0.f, 0.f, 0.f};

  const int r0 = tid >> 3;
  const int col8 = tid & 7;
  const int slot = col8 ^ (r0 & 7);
  const u16* ag0 = A + (size_t)(Mb + r0) * K + col8 * 8;
  const u16* ag1 = ag0 + (size_t)32 * K;
  const u16* ag2 = ag0 + (size_t)64 * K;
  const u16* ag3 = ag0 + (size_t)96 * K;
  const u16* bg0 = Bw + (size_t)(Nb + r0) * K + col8 * 8;
  const u16* bg1 = bg0 + (size_t)32 * K;
  u16* al0 = &As[0][r0 * 64 + slot * 8];
  u16* al1 = al0 + 32 * 64;
  u16* al2 = al0 + 64 * 64;
  u16* al3 = al0 + 96 * 64;
  u16* bl0 = &Bs[0][r0 * 64 + slot * 8];
  u16* bl1 = bl0 + 32 * 64;

  bf16x8 arA = *(const bf16x8*)ag0, arB = *(const bf16x8*)ag1;
  bf16x8 arC = *(const bf16x8*)ag2, arD = *(const bf16x8*)ag3;
  bf16x8 brA = *(const bf16x8*)bg0, brB = *(const bf16x8*)bg1;
  *(bf16x8*)al0 = arA; *(bf16x8*)al1 = arB;
  *(bf16x8*)al2 = arC; *(bf16x8*)al3 = arD;
  *(bf16x8*)bl0 = brA; *(bf16x8*)bl1 = brB;
  arA = *(const bf16x8*)(ag0 + 64); arB = *(const bf16x8*)(ag1 + 64);
  arC = *(const bf16x8*)(ag2 + 64); arD = *(const bf16x8*)(ag3 + 64);
  brA = *(const bf16x8*)(bg0 + 64); brB = *(const bf16x8*)(bg1 + 64);
  __syncthreads();

  const int swz = c & 7;
  const int NTI = 16;

  for (int t = 0; t < NTI; ++t) {
    const int cur = t & 1;
    if (t + 1 < NTI) {
      const int nbA = (cur ^ 1) * 8192;
      const int nbB = (cur ^ 1) * 4096;
      *(bf16x8*)(al0 + nbA) = arA; *(bf16x8*)(al1 + nbA) = arB;
      *(bf16x8*)(al2 + nbA) = arC; *(bf16x8*)(al3 + nbA) = arD;
      *(bf16x8*)(bl0 + nbB) = brA; *(bf16x8*)(bl1 + nbB) = brB;
      if (t + 2 < NTI) {
        arA = *(const bf16x8*)(ag0 + (t + 2) * 64);
        arB = *(const bf16x8*)(ag1 + (t + 2) * 64);
        arC = *(const bf16x8*)(ag2 + (t + 2) * 64);
        arD = *(const bf16x8*)(ag3 + (t + 2) * 64);
        brA = *(const bf16x8*)(bg0 + (t + 2) * 64);
        brB = *(const bf16x8*)(bg1 + (t + 2) * 64);
      }
    }
    const u16* AB = &As[cur][0];
    const u16* BB = &Bs[cur][0];
#pragma unroll
    for (int ks = 0; ks < 2; ks++) {
      const int koff = ((4 * ks + g) ^ swz) * 8;
      bf16x8 af[4], bfr[2];
#pragma unroll
      for (int mi = 0; mi < 4; mi++)
        af[mi] = *(const bf16x8*)&AB[(wr * 64 + mi * 16 + c) * 64 + koff];
#pragma unroll
      for (int ni = 0; ni < 2; ni++)
        bfr[ni] = *(const bf16x8*)&BB[(wc * 32 + ni * 16 + c) * 64 + koff];
#pragma unroll
      for (int mi = 0; mi < 4; mi++)
#pragma unroll
        for (int ni = 0; ni < 2; ni++)
          acc[mi][ni] = __builtin_amdgcn_mfma_f32_16x16x32_bf16(af[mi], bfr[ni], acc[mi][ni], 0, 0, 0);
    }
    asm volatile("s_waitcnt lgkmcnt(0)\n\ts_barrier" ::: "memory");
  }

#pragma unroll
  for (int mi = 0; mi < 4; mi++) {
#pragma unroll
    for (int ni = 0; ni < 2; ni++) {
      int n = Nb + wc * 32 + ni * 16 + c;
      float bv = bias[n];
#pragma unroll
      for (int r = 0; r < 4; r++) {
        int row = Mb + wr * 64 + mi * 16 + g * 4 + r;
        fo[(size_t)row * N + n] = acc[mi][ni][r] + bv;
      }
    }
  }
}

// Flash attention over COMPACTED kv, 4 waves x 32 q-rows (r19 structure).
__global__ __launch_bounds__(256, 3) void attn_kernel(
    const u16* __restrict__ qb, const u16* __restrict__ kb,
    const u16* __restrict__ vtb, const u16* __restrict__ mwg,
    const int* __restrict__ nvb, u16* __restrict__ ob) {
  __shared__ __align__(16) u16 Kl[2][64 * 64];
  __shared__ __align__(16) u16 Vl[2][64 * 64];
  __shared__ __align__(16) u16 MW[S_];

  const int tid = threadIdx.x;
  const int wv = tid >> 6, lane = tid & 63;
  const int g = lane >> 4, c = lane & 15;

  const int L = blockIdx.x;
  const int j = L >> 3;
  const int bh = ((L & 7) << 2) | (j >> 4);
  const int qi = j & 15;
  const int b = bh >> 4, h = bh & 15;
  const int q0 = qi * 128;
  const size_t bhbase = (size_t)bh * (S_ * HD);
  const int NT = (nvb[b] + 63) >> 6;

  ((uint4*)MW)[tid] = ((const uint4*)(mwg + b * S_))[tid];

  bf16x8 qf[2][2];
#pragma unroll
  for (int mi = 0; mi < 2; mi++)
#pragma unroll
    for (int ks = 0; ks < 2; ks++)
      qf[mi][ks] = *(const bf16x8*)(qb + bhbase +
                   (size_t)(q0 + wv * 32 + mi * 16 + c) * HD + ks * 32 + g * 8);

  f32x4 Oa[4][2];
#pragma unroll
  for (int di = 0; di < 4; di++)
#pragma unroll
    for (int mi = 0; mi < 2; mi++) Oa[di][mi] = f32x4{0.f, 0.f, 0.f, 0.f};
  f32x4 lacc[2];
  lacc[0] = f32x4{0.f, 0.f, 0.f, 0.f};
  lacc[1] = f32x4{0.f, 0.f, 0.f, 0.f};

  union { u32 u[4]; bf16x8 v; } ones;
#pragma unroll
  for (int w = 0; w < 4; w++) ones.u[w] = 0x3F803F80u;

  const int srow = tid >> 3;
  const int scol8 = tid & 7;
  const u16* kg1 = kb + bhbase + (size_t)srow * HD + scol8 * 8;
  const u16* kg2 = kg1 + (size_t)32 * HD;
  const u16* vg1 = vtb + bhbase + (size_t)srow * S_ + scol8 * 8;
  const u16* vg2 = vg1 + (size_t)32 * S_;
  const int wslot = scol8 ^ (srow & 7);
  u16* kld1 = &Kl[0][srow * 64 + wslot * 8];
  u16* kld2 = kld1 + 32 * 64;
  u16* vld1 = &Vl[0][srow * 64 + wslot * 8];
  u16* vld2 = vld1 + 32 * 64;

  bf16x8 krg[2], vrg[2];
  krg[0] = *(const bf16x8*)kg1;  krg[1] = *(const bf16x8*)kg2;
  vrg[0] = *(const bf16x8*)vg1;  vrg[1] = *(const bf16x8*)vg2;
  *(bf16x8*)kld1 = krg[0];  *(bf16x8*)kld2 = krg[1];
  *(bf16x8*)vld1 = vrg[0];  *(bf16x8*)vld2 = vrg[1];
  krg[0] = *(const bf16x8*)(kg1 + 4096);  krg[1] = *(const bf16x8*)(kg2 + 4096);
  vrg[0] = *(const bf16x8*)(vg1 + 64);    vrg[1] = *(const bf16x8*)(vg2 + 64);
  __syncthreads();

  const int swz = c & 7;

  for (int t = 0; t < NT; ++t) {
    const int cur = t & 1;
    if (t + 1 < NT) {
      const int nb = (cur ^ 1) * 4096;
      *(bf16x8*)(kld1 + nb) = krg[0];  *(bf16x8*)(kld2 + nb) = krg[1];
      *(bf16x8*)(vld1 + nb) = vrg[0];  *(bf16x8*)(vld2 + nb) = vrg[1];
      if (t + 2 < NT) {
        krg[0] = *(const bf16x8*)(kg1 + (t + 2) * 4096);
        krg[1] = *(const bf16x8*)(kg2 + (t + 2) * 4096);
        vrg[0] = *(const bf16x8*)(vg1 + (t + 2) * 64);
        vrg[1] = *(const bf16x8*)(vg2 + (t + 2) * 64);
      }
    }
    const u16* KB = &Kl[cur][0];
    const u16* VB = &Vl[cur][0];

    f32x4 Sa[4][2];
#pragma unroll
    for (int ni = 0; ni < 4; ni++)
#pragma unroll
      for (int mi = 0; mi < 2; mi++) Sa[ni][mi] = f32x4{0.f, 0.f, 0.f, 0.f};
    __builtin_amdgcn_s_setprio(1);
#pragma unroll
    for (int ks = 0; ks < 2; ks++) {
      bf16x8 kf[4];
#pragma unroll
      for (int ni = 0; ni < 4; ni++)
        kf[ni] = *(const bf16x8*)&KB[(ni * 16 + c) * 64 + (((4 * ks + g) ^ swz) * 8)];
#pragma unroll
      for (int ni = 0; ni < 4; ni++)
#pragma unroll
        for (int mi = 0; mi < 2; mi++)
          Sa[ni][mi] = __builtin_amdgcn_mfma_f32_16x16x32_bf16(kf[ni], qf[mi][ks], Sa[ni][mi], 0, 0, 0);
    }
    __builtin_amdgcn_s_setprio(0);

    bf16x8 Pa[2][2];
#pragma unroll
    for (int ks = 0; ks < 2; ks++) {
      uint4 mw = *(const uint4*)&MW[t * 64 + ks * 32 + g * 8];
#pragma unroll
      for (int mi = 0; mi < 2; mi++) {
        union { u32 u[4]; bf16x8 v; } pw;
        pw.u[0] = cvtpk(exp2a(Sa[2 * ks][mi][0]), exp2a(Sa[2 * ks][mi][1])) & mw.x;
        pw.u[1] = cvtpk(exp2a(Sa[2 * ks][mi][2]), exp2a(Sa[2 * ks][mi][3])) & mw.y;
        pw.u[2] = cvtpk(exp2a(Sa[2 * ks + 1][mi][0]), exp2a(Sa[2 * ks + 1][mi][1])) & mw.z;
        pw.u[3] = cvtpk(exp2a(Sa[2 * ks + 1][mi][2]), exp2a(Sa[2 * ks + 1][mi][3])) & mw.w;
        Pa[mi][ks] = pw.v;
      }
    }

    __builtin_amdgcn_s_setprio(1);
#pragma unroll
    for (int mi = 0; mi < 2; mi++) {
      lacc[mi] = __builtin_amdgcn_mfma_f32_16x16x32_bf16(ones.v, Pa[mi][0], lacc[mi], 0, 0, 0);
      lacc[mi] = __builtin_amdgcn_mfma_f32_16x16x32_bf16(ones.v, Pa[mi][1], lacc[mi], 0, 0, 0);
    }
#pragma unroll
    for (int ks = 0; ks < 2; ks++) {
      bf16x8 vf[4];
#pragma unroll
      for (int di = 0; di < 4; di++)
        vf[di] = *(const bf16x8*)&VB[(di * 16 + c) * 64 + (((4 * ks + g) ^ swz) * 8)];
#pragma unroll
      for (int di = 0; di < 4; di++)
#pragma unroll
        for (int mi = 0; mi < 2; mi++)
          Oa[di][mi] = __builtin_amdgcn_mfma_f32_16x16x32_bf16(vf[di], Pa[mi][ks], Oa[di][mi], 0, 0, 0);
    }
    __builtin_amdgcn_s_setprio(0);

    asm volatile("s_waitcnt lgkmcnt(0)\n\ts_barrier" ::: "memory");
  }

#pragma unroll
  for (int mi = 0; mi < 2; mi++) {
    float inv = 1.f / lacc[mi][0];
    int q = q0 + wv * 32 + mi * 16 + c;
    size_t base = ((size_t)(b * S_ + q)) * DM + (size_t)h * HD;
#pragma unroll
    for (int di = 0; di < 4; di++) {
      uint2 o;
      o.x = cvtpk(Oa[di][mi][0] * inv, Oa[di][mi][1] * inv);
      o.y = cvtpk(Oa[di][mi][2] * inv, Oa[di][mi][3] * inv);
      *(uint2*)(ob + base + di * 16 + g * 4) = o;
    }
  }
}

extern "C" void kernel_launch(void* const* d_in, const int* in_sizes, int n_in,
                              void* d_out, int out_size, void* d_ws, size_t ws_size,
                              hipStream_t stream) {
  const float* q  = (const float*)d_in[0];
  const int* kvm  = (const int*)d_in[1];
  const float* Wq = (const float*)d_in[2];
  const float* Wk = (const float*)d_in[3];
  const float* Wv = (const float*)d_in[4];
  const float* Wo = (const float*)d_in[5];
  const float* bo = (const float*)d_in[6];
  float* out = (float*)d_out;
  char* ws = (char*)d_ws;

  u16* Xbf   = (u16*)(ws);                       // 8 MB; reused as obuf post-gemm
  u16* Wcat  = (u16*)(ws + (8u << 20));          // 6 MB (Wq|Wk|Wv)
  u16* Wobf  = (u16*)(ws + (14u << 20));         // 2 MB
  u16* qbuf  = (u16*)(ws + (16u << 20));         // 8 MB (B,H,S,64), pre-scaled
  u16* kbuf  = (u16*)(ws + (24u << 20));         // 8 MB compacted
  u16* vtbuf = (u16*)(ws + (32u << 20));         // 8 MB (B,H,64,S) sigma, compacted
  u16* mwg   = (u16*)(ws + (40u << 20));         // 8 KB compacted mask words
  int* posb  = (int*)(ws + (41u << 20));         // 16 KB prefix positions
  int* nvb   = (int*)(ws + (42u << 20));         // 8 B totals
  u16* Xc    = (u16*)d_out;                      // 8 MB compacted X (d_out scratch)
  u16* obuf  = Xbf;

  mask_scan<<<B_, 256, 0, stream>>>(kvm, posb, nvb, mwg);
  cvt_all<<<2048, 256, 0, stream>>>(q, Wq, Wk, Wv, Wo, kvm, posb, nvb,
                                    Xbf, Wcat, Wobf, vtbuf, Xc);
  gemm_qkv<<<768, 512, 0, stream>>>(Xbf, Xc, Wcat, qbuf, kbuf, vtbuf, nvb);
  attn_kernel<<<512, 256, 0, stream>>>(qbuf, kbuf, vtbuf, mwg, nvb, obuf);
  gemm_n64<<<512, 256, 0, stream>>>(obuf, Wobf, bo, out);
}

// Round 27
// 97.169 us; speedup vs baseline: 1.1329x; 1.0042x over previous
//
#include <hip/hip_runtime.h>
#include <math.h>

#define B_ 2
#define S_ 2048
#define DM 1024
#define NH 16
#define HD 64

typedef unsigned short u16;
typedef unsigned int u32;
typedef __attribute__((ext_vector_type(8))) short bf16x8;
typedef __attribute__((ext_vector_type(4))) float f32x4;

// (1/sqrt(model_dim)) * log2(e): folded into Q at GEMM0 epilogue
#define C2SCALE 0.0450842200277800f

__device__ __forceinline__ u16 f2bf(float x) {
  unsigned u = __float_as_uint(x);
  u = (u + 0x7FFFu + ((u >> 16) & 1u)) >> 16;
  return (u16)u;
}

__device__ __forceinline__ u32 cvtpk(float lo, float hi) {
  u32 r;
  asm("v_cvt_pk_bf16_f32 %0, %1, %2" : "=v"(r) : "v"(lo), "v"(hi));
  return r;
}

__device__ __forceinline__ float exp2a(float x) {
  float r;
  asm("v_exp_f32 %0, %1" : "=v"(r) : "v"(x));
  return r;
}

// sigma position within a 64-chunk (same permutation as the V^T producer)
__device__ __forceinline__ int sigpos(int w6) {
  return ((w6 >> 5) << 5) | (((w6 >> 2) & 3) << 3) | (((w6 >> 4) & 1) << 2) | (w6 & 3);
}

// per-batch exclusive prefix scan of kv_mask -> inverse map invpos[p] = s
// (valid rows only), totals nvb, sigma-ordered COMPACTED mask words.
__global__ void mask_scan(const int* __restrict__ kvm, int* __restrict__ invpos,
                          int* __restrict__ nvb, u16* __restrict__ mwg) {
  const int b = blockIdx.x;
  const int tid = threadIdx.x;  // 256
  const int lane = tid & 63, wv = tid >> 6;
  __shared__ int wsum[4];
  int v[8], s = 0;
  const int base = b * S_ + tid * 8;
#pragma unroll
  for (int j = 0; j < 8; j++) { v[j] = kvm[base + j] ? 1 : 0; s += v[j]; }
  int sc = s;
#pragma unroll
  for (int off = 1; off < 64; off <<= 1) {
    int t = __shfl_up(sc, off, 64);
    if (lane >= off) sc += t;
  }
  if (lane == 63) wsum[wv] = sc;
  __syncthreads();
  int woff = 0;
#pragma unroll
  for (int w = 0; w < 4; w++) woff += (w < wv) ? wsum[w] : 0;
  int run = woff + sc - s;  // exclusive prefix for this thread's chunk
#pragma unroll
  for (int j = 0; j < 8; j++) {
    if (v[j]) invpos[b * S_ + run] = tid * 8 + j;
    run += v[j];
  }
  const int total = wsum[0] + wsum[1] + wsum[2] + wsum[3];
  if (tid == 0) nvb[b] = total;
  for (int i = tid; i < S_; i += 256)
    mwg[b * S_ + (i & ~63) + sigpos(i & 63)] = (i < total) ? 0xFFFFu : 0u;
}

// fused f32->bf16 converts + V^T pad-column zeroing (PV NaN safety).
__global__ void cvt_all(const float* __restrict__ q, const float* __restrict__ Wq,
                        const float* __restrict__ Wk, const float* __restrict__ Wv,
                        const float* __restrict__ Wo, const int* __restrict__ nvb,
                        u16* __restrict__ Xbf, u16* __restrict__ Wcat,
                        u16* __restrict__ Wobf, u16* __restrict__ vtbuf) {
  const int NQ4 = (B_ * S_ * DM) / 4;
  const int NW4 = (DM * DM) / 4;
  const int total = NQ4 + 4 * NW4;
  int i = blockIdx.x * blockDim.x + threadIdx.x;
  int stride = gridDim.x * blockDim.x;
  // zero V^T pad columns [nv, ceil64(nv)) for every (bh, d)
  for (int idx = i; idx < B_ * NH * HD * 64; idx += stride) {
    int col = idx & 63;
    int dd = (idx >> 6) & 63;
    int bh = idx >> 12;
    int nv = nvb[bh >> 4];
    int padw = ((nv + 63) & ~63) - nv;
    if (col < padw)
      vtbuf[((size_t)bh * HD + dd) * S_ + nv + col] = 0;
  }
  for (; i < total; i += stride) {
    const float* src;
    u16* dst;
    if (i < NQ4) {
      src = q + (size_t)i * 4; dst = Xbf + (size_t)i * 4;
    } else {
      int t = i - NQ4;
      if (t < NW4)            { src = Wq + (size_t)t * 4; dst = Wcat + (size_t)t * 4; }
      else if (t < 2 * NW4)   { src = Wk + (size_t)(t - NW4) * 4;     dst = Wcat + DM * DM + (size_t)(t - NW4) * 4; }
      else if (t < 3 * NW4)   { src = Wv + (size_t)(t - 2 * NW4) * 4; dst = Wcat + 2 * DM * DM + (size_t)(t - 2 * NW4) * 4; }
      else                    { src = Wo + (size_t)(t - 3 * NW4) * 4; dst = Wobf + (size_t)(t - 3 * NW4) * 4; }
    }
    float4 v = *(const float4*)src;
    ushort4 o;
    o.x = f2bf(v.x); o.y = f2bf(v.y); o.z = f2bf(v.z); o.w = f2bf(v.w);
    *(ushort4*)dst = o;
  }
}

// Unified projection GEMM, BK=64, 8 waves (4M x 2N), 128x128 tile, reg-staged
// double-buffered XOR-swizzled LDS (64 KB), lgkm-only barrier. (champion)
// KV blocks gather A-rows directly from Xbf via invpos (no Xc buffer).
__global__ __launch_bounds__(512, 4) void gemm_qkv(
    const u16* __restrict__ Xbf, const int* __restrict__ invpos,
    const u16* __restrict__ Wcat, u16* __restrict__ qo, u16* __restrict__ ko,
    u16* __restrict__ vo, const int* __restrict__ nvb) {
  const int K = DM;
  const int Lraw = blockIdx.x;
  const int Ls = (Lraw & 7) * 96 + (Lraw >> 3);

  const int tid = threadIdx.x;
  const int wv = tid >> 6, lane = tid & 63;
  const int g = lane >> 4, c = lane & 15;
  const int wr = wv >> 1, wc = wv & 1;
  const int r1 = tid >> 3;
  const int col8 = tid & 7;

  int Mb, nglob, bkv = 0, nv = 1 << 30;
  size_t arow1, arow2;   // flat Xbf row indices for this thread's staging rows
  if (Ls < 256) {
    Mb = (Ls & 31) << 7;
    nglob = (Ls >> 5) << 7;
    arow1 = (size_t)(Mb + r1);
    arow2 = (size_t)(Mb + r1 + 64);
  } else {
    int L2 = Ls - 256;
    bkv = L2 >> 8;
    int L3 = L2 & 255;
    Mb = (L3 & 15) << 7;
    nglob = 1024 + ((L3 >> 4) << 7);
    nv = nvb[bkv];
    if (Mb >= nv) return;
    int p1 = Mb + r1, p2 = Mb + r1 + 64;
    int s1 = (p1 < nv) ? invpos[bkv * S_ + p1] : 0;
    int s2 = (p2 < nv) ? invpos[bkv * S_ + p2] : 0;
    arow1 = (size_t)bkv * S_ + s1;
    arow2 = (size_t)bkv * S_ + s2;
  }

  __shared__ __align__(16) u16 As[2][128 * 64];
  __shared__ __align__(16) u16 Bs[2][128 * 64];

  f32x4 acc[2][4];
#pragma unroll
  for (int i = 0; i < 2; i++)
#pragma unroll
    for (int j = 0; j < 4; j++) acc[i][j] = f32x4{0.f, 0.f, 0.f, 0.f};

  const u16* ag1 = Xbf + arow1 * K + col8 * 8;
  const u16* ag2 = Xbf + arow2 * K + col8 * 8;
  const u16* bg1 = Wcat + (size_t)(nglob + r1) * K + col8 * 8;
  const u16* bg2 = bg1 + (size_t)64 * K;
  const int slot = col8 ^ (r1 & 7);
  u16* al1 = &As[0][r1 * 64 + slot * 8];
  u16* al2 = al1 + 64 * 64;
  u16* bl1 = &Bs[0][r1 * 64 + slot * 8];
  u16* bl2 = bl1 + 64 * 64;

  bf16x8 ar0 = *(const bf16x8*)ag1, ar1 = *(const bf16x8*)ag2;
  bf16x8 br0 = *(const bf16x8*)bg1, br1 = *(const bf16x8*)bg2;
  *(bf16x8*)al1 = ar0; *(bf16x8*)al2 = ar1;
  *(bf16x8*)bl1 = br0; *(bf16x8*)bl2 = br1;
  ar0 = *(const bf16x8*)(ag1 + 64); ar1 = *(const bf16x8*)(ag2 + 64);
  br0 = *(const bf16x8*)(bg1 + 64); br1 = *(const bf16x8*)(bg2 + 64);
  __syncthreads();

  const int swz = c & 7;
  const int NTI = 16;

  for (int t = 0; t < NTI; ++t) {
    const int cur = t & 1;
    if (t + 1 < NTI) {
      const int nb = (cur ^ 1) * 8192;
      *(bf16x8*)(al1 + nb) = ar0; *(bf16x8*)(al2 + nb) = ar1;
      *(bf16x8*)(bl1 + nb) = br0; *(bf16x8*)(bl2 + nb) = br1;
      if (t + 2 < NTI) {
        ar0 = *(const bf16x8*)(ag1 + (t + 2) * 64);
        ar1 = *(const bf16x8*)(ag2 + (t + 2) * 64);
        br0 = *(const bf16x8*)(bg1 + (t + 2) * 64);
        br1 = *(const bf16x8*)(bg2 + (t + 2) * 64);
      }
    }
    const u16* AB = &As[cur][0];
    const u16* BB = &Bs[cur][0];
#pragma unroll
    for (int ks = 0; ks < 2; ks++) {
      const int koff = ((4 * ks + g) ^ swz) * 8;
      bf16x8 af[2], bfr[4];
#pragma unroll
      for (int mi = 0; mi < 2; mi++)
        af[mi] = *(const bf16x8*)&AB[(wr * 32 + mi * 16 + c) * 64 + koff];
#pragma unroll
      for (int ni = 0; ni < 4; ni++)
        bfr[ni] = *(const bf16x8*)&BB[(wc * 64 + ni * 16 + c) * 64 + koff];
#pragma unroll
      for (int mi = 0; mi < 2; mi++)
#pragma unroll
        for (int ni = 0; ni < 4; ni++)
          acc[mi][ni] = __builtin_amdgcn_mfma_f32_16x16x32_bf16(af[mi], bfr[ni], acc[mi][ni], 0, 0, 0);
    }
    asm volatile("s_waitcnt lgkmcnt(0)\n\ts_barrier" ::: "memory");
  }

  const int nbase = nglob + wc * 64 + c;
  const int which = nbase >> 10;
  if (which == 0) {
#pragma unroll
    for (int mi = 0; mi < 2; mi++) {
#pragma unroll
      for (int ni = 0; ni < 4; ni++) {
        int nn = nbase + ni * 16;
        int h = nn >> 6, d = nn & 63;
#pragma unroll
        for (int r = 0; r < 4; r++) {
          int row = Mb + wr * 32 + mi * 16 + g * 4 + r;
          int b0 = row >> 11, s0 = row & 2047;
          qo[(((size_t)(b0 * NH + h)) * S_ + s0) * HD + d] =
              f2bf(acc[mi][ni][r] * C2SCALE);
        }
      }
    }
  } else if (which == 1) {
#pragma unroll
    for (int mi = 0; mi < 2; mi++) {
#pragma unroll
      for (int r = 0; r < 4; r++) {
        int p = Mb + wr * 32 + mi * 16 + g * 4 + r;
        if (p < nv) {
#pragma unroll
          for (int ni = 0; ni < 4; ni++) {
            int nn = (nbase + ni * 16) & 1023;
            ko[((size_t)(bkv * NH + (nn >> 6)) * S_ + p) * HD + (nn & 63)] =
                f2bf(acc[mi][ni][r]);
          }
        }
      }
    }
  } else {
#pragma unroll
    for (int mi = 0; mi < 2; mi++) {
#pragma unroll
      for (int r = 0; r < 4; r++) {
        int p = Mb + wr * 32 + mi * 16 + g * 4 + r;
        if (p < nv) {
          int dst = (p & ~63) + sigpos(p & 63);
#pragma unroll
          for (int ni = 0; ni < 4; ni++) {
            int nn = (nbase + ni * 16) & 1023;
            vo[((size_t)((bkv * NH + (nn >> 6)) * HD + (nn & 63))) * S_ + dst] =
                f2bf(acc[mi][ni][r]);
          }
        }
      }
    }
  }
}

// GEMM1: out[4096,1024] = A @ Wo^T + bo. 128x64 tile, 512 blocks, BK=64
// (16 k-iters), reg-staged dbuf XOR-swizzled LDS, lgkm-only barrier. (r21)
__global__ __launch_bounds__(256, 3) void gemm_n64(
    const u16* __restrict__ A, const u16* __restrict__ Bw,
    const float* __restrict__ bias, float* __restrict__ fo) {
  __shared__ __align__(16) u16 As[2][128 * 64];
  __shared__ __align__(16) u16 Bs[2][64 * 64];
  const int K = DM, N = DM;
  const int tid = threadIdx.x;
  const int wv = tid >> 6, lane = tid & 63;
  const int g = lane >> 4, c = lane & 15;
  const int wr = wv >> 1, wc = wv & 1;
  const int L = blockIdx.x;
  const int Ls = (L & 7) * 64 + (L >> 3);
  const int Mb = (Ls & 31) << 7, Nb = (Ls >> 5) << 6;

  f32x4 acc[4][2];
#pragma unroll
  for (int i = 0; i < 4; i++)
#pragma unroll
    for (int j = 0; j < 2; j++) acc[i][j] = f32x4{0.f, 0.f, 0.f, 0.f};

  const int r0 = tid >> 3;
  const int col8 = tid & 7;
  const int slot = col8 ^ (r0 & 7);
  const u16* ag0 = A + (size_t)(Mb + r0) * K + col8 * 8;
  const u16* ag1 = ag0 + (size_t)32 * K;
  const u16* ag2 = ag0 + (size_t)64 * K;
  const u16* ag3 = ag0 + (size_t)96 * K;
  const u16* bg0 = Bw + (size_t)(Nb + r0) * K + col8 * 8;
  const u16* bg1 = bg0 + (size_t)32 * K;
  u16* al0 = &As[0][r0 * 64 + slot * 8];
  u16* al1 = al0 + 32 * 64;
  u16* al2 = al0 + 64 * 64;
  u16* al3 = al0 + 96 * 64;
  u16* bl0 = &Bs[0][r0 * 64 + slot * 8];
  u16* bl1 = bl0 + 32 * 64;

  bf16x8 arA = *(const bf16x8*)ag0, arB = *(const bf16x8*)ag1;
  bf16x8 arC = *(const bf16x8*)ag2, arD = *(const bf16x8*)ag3;
  bf16x8 brA = *(const bf16x8*)bg0, brB = *(const bf16x8*)bg1;
  *(bf16x8*)al0 = arA; *(bf16x8*)al1 = arB;
  *(bf16x8*)al2 = arC; *(bf16x8*)al3 = arD;
  *(bf16x8*)bl0 = brA; *(bf16x8*)bl1 = brB;
  arA = *(const bf16x8*)(ag0 + 64); arB = *(const bf16x8*)(ag1 + 64);
  arC = *(const bf16x8*)(ag2 + 64); arD = *(const bf16x8*)(ag3 + 64);
  brA = *(const bf16x8*)(bg0 + 64); brB = *(const bf16x8*)(bg1 + 64);
  __syncthreads();

  const int swz = c & 7;
  const int NTI = 16;

  for (int t = 0; t < NTI; ++t) {
    const int cur = t & 1;
    if (t + 1 < NTI) {
      const int nbA = (cur ^ 1) * 8192;
      const int nbB = (cur ^ 1) * 4096;
      *(bf16x8*)(al0 + nbA) = arA; *(bf16x8*)(al1 + nbA) = arB;
      *(bf16x8*)(al2 + nbA) = arC; *(bf16x8*)(al3 + nbA) = arD;
      *(bf16x8*)(bl0 + nbB) = brA; *(bf16x8*)(bl1 + nbB) = brB;
      if (t + 2 < NTI) {
        arA = *(const bf16x8*)(ag0 + (t + 2) * 64);
        arB = *(const bf16x8*)(ag1 + (t + 2) * 64);
        arC = *(const bf16x8*)(ag2 + (t + 2) * 64);
        arD = *(const bf16x8*)(ag3 + (t + 2) * 64);
        brA = *(const bf16x8*)(bg0 + (t + 2) * 64);
        brB = *(const bf16x8*)(bg1 + (t + 2) * 64);
      }
    }
    const u16* AB = &As[cur][0];
    const u16* BB = &Bs[cur][0];
#pragma unroll
    for (int ks = 0; ks < 2; ks++) {
      const int koff = ((4 * ks + g) ^ swz) * 8;
      bf16x8 af[4], bfr[2];
#pragma unroll
      for (int mi = 0; mi < 4; mi++)
        af[mi] = *(const bf16x8*)&AB[(wr * 64 + mi * 16 + c) * 64 + koff];
#pragma unroll
      for (int ni = 0; ni < 2; ni++)
        bfr[ni] = *(const bf16x8*)&BB[(wc * 32 + ni * 16 + c) * 64 + koff];
#pragma unroll
      for (int mi = 0; mi < 4; mi++)
#pragma unroll
        for (int ni = 0; ni < 2; ni++)
          acc[mi][ni] = __builtin_amdgcn_mfma_f32_16x16x32_bf16(af[mi], bfr[ni], acc[mi][ni], 0, 0, 0);
    }
    asm volatile("s_waitcnt lgkmcnt(0)\n\ts_barrier" ::: "memory");
  }

#pragma unroll
  for (int mi = 0; mi < 4; mi++) {
#pragma unroll
    for (int ni = 0; ni < 2; ni++) {
      int n = Nb + wc * 32 + ni * 16 + c;
      float bv = bias[n];
#pragma unroll
      for (int r = 0; r < 4; r++) {
        int row = Mb + wr * 64 + mi * 16 + g * 4 + r;
        fo[(size_t)row * N + n] = acc[mi][ni][r] + bv;
      }
    }
  }
}

// Flash attention over COMPACTED kv, 4 waves x 32 q-rows (r19 structure).
__global__ __launch_bounds__(256, 3) void attn_kernel(
    const u16* __restrict__ qb, const u16* __restrict__ kb,
    const u16* __restrict__ vtb, const u16* __restrict__ mwg,
    const int* __restrict__ nvb, u16* __restrict__ ob) {
  __shared__ __align__(16) u16 Kl[2][64 * 64];
  __shared__ __align__(16) u16 Vl[2][64 * 64];
  __shared__ __align__(16) u16 MW[S_];

  const int tid = threadIdx.x;
  const int wv = tid >> 6, lane = tid & 63;
  const int g = lane >> 4, c = lane & 15;

  const int L = blockIdx.x;
  const int j = L >> 3;
  const int bh = ((L & 7) << 2) | (j >> 4);
  const int qi = j & 15;
  const int b = bh >> 4, h = bh & 15;
  const int q0 = qi * 128;
  const size_t bhbase = (size_t)bh * (S_ * HD);
  const int NT = (nvb[b] + 63) >> 6;

  ((uint4*)MW)[tid] = ((const uint4*)(mwg + b * S_))[tid];

  bf16x8 qf[2][2];
#pragma unroll
  for (int mi = 0; mi < 2; mi++)
#pragma unroll
    for (int ks = 0; ks < 2; ks++)
      qf[mi][ks] = *(const bf16x8*)(qb + bhbase +
                   (size_t)(q0 + wv * 32 + mi * 16 + c) * HD + ks * 32 + g * 8);

  f32x4 Oa[4][2];
#pragma unroll
  for (int di = 0; di < 4; di++)
#pragma unroll
    for (int mi = 0; mi < 2; mi++) Oa[di][mi] = f32x4{0.f, 0.f, 0.f, 0.f};
  f32x4 lacc[2];
  lacc[0] = f32x4{0.f, 0.f, 0.f, 0.f};
  lacc[1] = f32x4{0.f, 0.f, 0.f, 0.f};

  union { u32 u[4]; bf16x8 v; } ones;
#pragma unroll
  for (int w = 0; w < 4; w++) ones.u[w] = 0x3F803F80u;

  const int srow = tid >> 3;
  const int scol8 = tid & 7;
  const u16* kg1 = kb + bhbase + (size_t)srow * HD + scol8 * 8;
  const u16* kg2 = kg1 + (size_t)32 * HD;
  const u16* vg1 = vtb + bhbase + (size_t)srow * S_ + scol8 * 8;
  const u16* vg2 = vg1 + (size_t)32 * S_;
  const int wslot = scol8 ^ (srow & 7);
  u16* kld1 = &Kl[0][srow * 64 + wslot * 8];
  u16* kld2 = kld1 + 32 * 64;
  u16* vld1 = &Vl[0][srow * 64 + wslot * 8];
  u16* vld2 = vld1 + 32 * 64;

  bf16x8 krg[2], vrg[2];
  krg[0] = *(const bf16x8*)kg1;  krg[1] = *(const bf16x8*)kg2;
  vrg[0] = *(const bf16x8*)vg1;  vrg[1] = *(const bf16x8*)vg2;
  *(bf16x8*)kld1 = krg[0];  *(bf16x8*)kld2 = krg[1];
  *(bf16x8*)vld1 = vrg[0];  *(bf16x8*)vld2 = vrg[1];
  krg[0] = *(const bf16x8*)(kg1 + 4096);  krg[1] = *(const bf16x8*)(kg2 + 4096);
  vrg[0] = *(const bf16x8*)(vg1 + 64);    vrg[1] = *(const bf16x8*)(vg2 + 64);
  __syncthreads();

  const int swz = c & 7;

  for (int t = 0; t < NT; ++t) {
    const int cur = t & 1;
    if (t + 1 < NT) {
      const int nb = (cur ^ 1) * 4096;
      *(bf16x8*)(kld1 + nb) = krg[0];  *(bf16x8*)(kld2 + nb) = krg[1];
      *(bf16x8*)(vld1 + nb) = vrg[0];  *(bf16x8*)(vld2 + nb) = vrg[1];
      if (t + 2 < NT) {
        krg[0] = *(const bf16x8*)(kg1 + (t + 2) * 4096);
        krg[1] = *(const bf16x8*)(kg2 + (t + 2) * 4096);
        vrg[0] = *(const bf16x8*)(vg1 + (t + 2) * 64);
        vrg[1] = *(const bf16x8*)(vg2 + (t + 2) * 64);
      }
    }
    const u16* KB = &Kl[cur][0];
    const u16* VB = &Vl[cur][0];

    f32x4 Sa[4][2];
#pragma unroll
    for (int ni = 0; ni < 4; ni++)
#pragma unroll
      for (int mi = 0; mi < 2; mi++) Sa[ni][mi] = f32x4{0.f, 0.f, 0.f, 0.f};
    __builtin_amdgcn_s_setprio(1);
#pragma unroll
    for (int ks = 0; ks < 2; ks++) {
      bf16x8 kf[4];
#pragma unroll
      for (int ni = 0; ni < 4; ni++)
        kf[ni] = *(const bf16x8*)&KB[(ni * 16 + c) * 64 + (((4 * ks + g) ^ swz) * 8)];
#pragma unroll
      for (int ni = 0; ni < 4; ni++)
#pragma unroll
        for (int mi = 0; mi < 2; mi++)
          Sa[ni][mi] = __builtin_amdgcn_mfma_f32_16x16x32_bf16(kf[ni], qf[mi][ks], Sa[ni][mi], 0, 0, 0);
    }
    __builtin_amdgcn_s_setprio(0);

    bf16x8 Pa[2][2];
#pragma unroll
    for (int ks = 0; ks < 2; ks++) {
      uint4 mw = *(const uint4*)&MW[t * 64 + ks * 32 + g * 8];
#pragma unroll
      for (int mi = 0; mi < 2; mi++) {
        union { u32 u[4]; bf16x8 v; } pw;
        pw.u[0] = cvtpk(exp2a(Sa[2 * ks][mi][0]), exp2a(Sa[2 * ks][mi][1])) & mw.x;
        pw.u[1] = cvtpk(exp2a(Sa[2 * ks][mi][2]), exp2a(Sa[2 * ks][mi][3])) & mw.y;
        pw.u[2] = cvtpk(exp2a(Sa[2 * ks + 1][mi][0]), exp2a(Sa[2 * ks + 1][mi][1])) & mw.z;
        pw.u[3] = cvtpk(exp2a(Sa[2 * ks + 1][mi][2]), exp2a(Sa[2 * ks + 1][mi][3])) & mw.w;
        Pa[mi][ks] = pw.v;
      }
    }

    __builtin_amdgcn_s_setprio(1);
#pragma unroll
    for (int mi = 0; mi < 2; mi++) {
      lacc[mi] = __builtin_amdgcn_mfma_f32_16x16x32_bf16(ones.v, Pa[mi][0], lacc[mi], 0, 0, 0);
      lacc[mi] = __builtin_amdgcn_mfma_f32_16x16x32_bf16(ones.v, Pa[mi][1], lacc[mi], 0, 0, 0);
    }
#pragma unroll
    for (int ks = 0; ks < 2; ks++) {
      bf16x8 vf[4];
#pragma unroll
      for (int di = 0; di < 4; di++)
        vf[di] = *(const bf16x8*)&VB[(di * 16 + c) * 64 + (((4 * ks + g) ^ swz) * 8)];
#pragma unroll
      for (int di = 0; di < 4; di++)
#pragma unroll
        for (int mi = 0; mi < 2; mi++)
          Oa[di][mi] = __builtin_amdgcn_mfma_f32_16x16x32_bf16(vf[di], Pa[mi][ks], Oa[di][mi], 0, 0, 0);
    }
    __builtin_amdgcn_s_setprio(0);

    asm volatile("s_waitcnt lgkmcnt(0)\n\ts_barrier" ::: "memory");
  }

#pragma unroll
  for (int mi = 0; mi < 2; mi++) {
    float inv = 1.f / lacc[mi][0];
    int q = q0 + wv * 32 + mi * 16 + c;
    size_t base = ((size_t)(b * S_ + q)) * DM + (size_t)h * HD;
#pragma unroll
    for (int di = 0; di < 4; di++) {
      uint2 o;
      o.x = cvtpk(Oa[di][mi][0] * inv, Oa[di][mi][1] * inv);
      o.y = cvtpk(Oa[di][mi][2] * inv, Oa[di][mi][3] * inv);
      *(uint2*)(ob + base + di * 16 + g * 4) = o;
    }
  }
}

extern "C" void kernel_launch(void* const* d_in, const int* in_sizes, int n_in,
                              void* d_out, int out_size, void* d_ws, size_t ws_size,
                              hipStream_t stream) {
  const float* q  = (const float*)d_in[0];
  const int* kvm  = (const int*)d_in[1];
  const float* Wq = (const float*)d_in[2];
  const float* Wk = (const float*)d_in[3];
  const float* Wv = (const float*)d_in[4];
  const float* Wo = (const float*)d_in[5];
  const float* bo = (const float*)d_in[6];
  float* out = (float*)d_out;
  char* ws = (char*)d_ws;

  u16* Xbf   = (u16*)(ws);                       // 8 MB; reused as obuf post-gemm
  u16* Wcat  = (u16*)(ws + (8u << 20));          // 6 MB (Wq|Wk|Wv)
  u16* Wobf  = (u16*)(ws + (14u << 20));         // 2 MB
  u16* qbuf  = (u16*)(ws + (16u << 20));         // 8 MB (B,H,S,64), pre-scaled
  u16* kbuf  = (u16*)(ws + (24u << 20));         // 8 MB compacted
  u16* vtbuf = (u16*)(ws + (32u << 20));         // 8 MB (B,H,64,S) sigma, compacted
  u16* mwg   = (u16*)(ws + (40u << 20));         // 8 KB compacted mask words
  int* invpos = (int*)(ws + (41u << 20));        // 16 KB inverse positions
  int* nvb   = (int*)(ws + (42u << 20));         // 8 B totals
  u16* obuf  = Xbf;

  mask_scan<<<B_, 256, 0, stream>>>(kvm, invpos, nvb, mwg);
  cvt_all<<<2048, 256, 0, stream>>>(q, Wq, Wk, Wv, Wo, nvb,
                                    Xbf, Wcat, Wobf, vtbuf);
  gemm_qkv<<<768, 512, 0, stream>>>(Xbf, invpos, Wcat, qbuf, kbuf, vtbuf, nvb);
  attn_kernel<<<512, 256, 0, stream>>>(qbuf, kbuf, vtbuf, mwg, nvb, obuf);
  gemm_n64<<<512, 256, 0, stream>>>(obuf, Wobf, bo, out);
}